// Round 1
// baseline (661.381 us; speedup 1.0000x reference)
//
#include <hip/hip_runtime.h>
#include <hip/hip_bf16.h>

// out[b,s,e] = sum_h cell_states[b,s,e,h] * W[e,h] + bias[e]
// B=4, S=512, E=64, H=1024 -> 131072 output dots of length 1024 (contiguous h).
// Memory-bound: 512 MiB streamed once. One wave (64 lanes) per output element,
// float4 coalesced loads (16B/lane), shfl butterfly reduction.

#define H_DIM 1024
#define E_DIM 64

__global__ __launch_bounds__(256) void Cell_to_Entity_78735340470739_kernel(
    const float* __restrict__ x,     // [n_out, H]
    const float* __restrict__ W,     // [E, H]
    const float* __restrict__ bias,  // [E]
    float* __restrict__ out,         // [n_out]
    int n_out)
{
    const int wave_in_block = threadIdx.x >> 6;
    const int lane          = threadIdx.x & 63;
    const int o = blockIdx.x * (blockDim.x >> 6) + wave_in_block;
    if (o >= n_out) return;

    const int e = o & (E_DIM - 1);

    const float4* __restrict__ xp = (const float4*)(x + (size_t)o * H_DIM);
    const float4* __restrict__ wp = (const float4*)(W + (size_t)e * H_DIM);

    float acc = 0.0f;
#pragma unroll
    for (int k = 0; k < 4; ++k) {
        const float4 xv = xp[lane + k * 64];
        const float4 wv = wp[lane + k * 64];
        acc += xv.x * wv.x + xv.y * wv.y + xv.z * wv.z + xv.w * wv.w;
    }

    // 64-lane butterfly reduction
#pragma unroll
    for (int off = 32; off > 0; off >>= 1)
        acc += __shfl_down(acc, off, 64);

    if (lane == 0)
        out[o] = acc + bias[e];
}

extern "C" void kernel_launch(void* const* d_in, const int* in_sizes, int n_in,
                              void* d_out, int out_size, void* d_ws, size_t ws_size,
                              hipStream_t stream) {
    const float* x    = (const float*)d_in[0];  // cell_states (B,S,E,H) fp32
    const float* W    = (const float*)d_in[1];  // (E,H) fp32
    const float* bias = (const float*)d_in[2];  // (E,) fp32
    float* out        = (float*)d_out;          // (B,S,E) fp32

    const int n_out = out_size;                 // 131072
    const int waves_per_block = 4;              // 256 threads
    const int blocks = (n_out + waves_per_block - 1) / waves_per_block;

    Cell_to_Entity_78735340470739_kernel<<<blocks, 256, 0, stream>>>(
        x, W, bias, out, n_out);
}

// Round 3
// 644.878 us; speedup vs baseline: 1.0256x; 1.0256x over previous
//
#include <hip/hip_runtime.h>
#include <hip/hip_bf16.h>

// out[b,s,e] = sum_h cell_states[b,s,e,h] * W[e,h] + bias[e]
// B=4, S=512, E=64, H=1024. N = B*S*E = 131072 rows of length H=1024.
// Rows with the same e (= row_index & 63) share W[e] (4 KiB) and bias[e].
//
// Strategy: persistent waves. Each wave is pinned to one e, loads W[e] into
// 16 VGPRs (4 x float4) + bias once, then strides over its share of the 2048
// rows for that e, 2 rows per iteration (8 independent 16B loads in flight).
// x is streamed once -> nontemporal loads to avoid L2 pollution.

#define H_DIM 1024
#define E_DIM 64

typedef float v4f __attribute__((ext_vector_type(4)));  // native vector: OK for nontemporal builtins

__global__ __launch_bounds__(256) void Cell_to_Entity_78735340470739_kernel(
    const float* __restrict__ x,     // [N, H]
    const float* __restrict__ W,     // [E, H]
    const float* __restrict__ bias,  // [E]
    float* __restrict__ out,         // [N]
    int n_out)
{
    const int lane    = threadIdx.x & 63;
    const int wave    = (int)((blockIdx.x * blockDim.x + threadIdx.x) >> 6);
    const int n_waves = (int)((gridDim.x * blockDim.x) >> 6);

    const int e           = wave & (E_DIM - 1);
    const int waves_per_e = n_waves >> 6;          // waves sharing this e
    const int r0          = wave >> 6;             // starting row (per-e index)
    const int R           = n_out >> 6;            // rows per e (B*S = 2048)

    // Cache W[e] row in registers, layout matching the x-load pattern.
    const v4f* __restrict__ wp = (const v4f*)(W + (size_t)e * H_DIM);
    const v4f w0 = wp[lane];
    const v4f w1 = wp[lane + 64];
    const v4f w2 = wp[lane + 128];
    const v4f w3 = wp[lane + 192];
    const float be = bias[e];

    int r = r0;
    // Main loop: two rows per iteration for ILP.
    for (; r + waves_per_e < R; r += 2 * waves_per_e) {
        const int oa = r * E_DIM + e;
        const int ob = (r + waves_per_e) * E_DIM + e;
        const v4f* __restrict__ xa = (const v4f*)(x + (size_t)oa * H_DIM);
        const v4f* __restrict__ xb = (const v4f*)(x + (size_t)ob * H_DIM);

        const v4f a0 = __builtin_nontemporal_load(&xa[lane]);
        const v4f a1 = __builtin_nontemporal_load(&xa[lane + 64]);
        const v4f a2 = __builtin_nontemporal_load(&xa[lane + 128]);
        const v4f a3 = __builtin_nontemporal_load(&xa[lane + 192]);
        const v4f b0 = __builtin_nontemporal_load(&xb[lane]);
        const v4f b1 = __builtin_nontemporal_load(&xb[lane + 64]);
        const v4f b2 = __builtin_nontemporal_load(&xb[lane + 128]);
        const v4f b3 = __builtin_nontemporal_load(&xb[lane + 192]);

        float acc_a = a0.x*w0.x + a0.y*w0.y + a0.z*w0.z + a0.w*w0.w
                    + a1.x*w1.x + a1.y*w1.y + a1.z*w1.z + a1.w*w1.w
                    + a2.x*w2.x + a2.y*w2.y + a2.z*w2.z + a2.w*w2.w
                    + a3.x*w3.x + a3.y*w3.y + a3.z*w3.z + a3.w*w3.w;
        float acc_b = b0.x*w0.x + b0.y*w0.y + b0.z*w0.z + b0.w*w0.w
                    + b1.x*w1.x + b1.y*w1.y + b1.z*w1.z + b1.w*w1.w
                    + b2.x*w2.x + b2.y*w2.y + b2.z*w2.z + b2.w*w2.w
                    + b3.x*w3.x + b3.y*w3.y + b3.z*w3.z + b3.w*w3.w;

        // Two independent 64-lane butterfly reductions (interleaved by compiler).
#pragma unroll
        for (int off = 32; off > 0; off >>= 1) {
            acc_a += __shfl_down(acc_a, off, 64);
            acc_b += __shfl_down(acc_b, off, 64);
        }
        if (lane == 0) {
            out[oa] = acc_a + be;
            out[ob] = acc_b + be;
        }
    }
    // Tail: single row.
    for (; r < R; r += waves_per_e) {
        const int o = r * E_DIM + e;
        const v4f* __restrict__ xp = (const v4f*)(x + (size_t)o * H_DIM);
        const v4f a0 = __builtin_nontemporal_load(&xp[lane]);
        const v4f a1 = __builtin_nontemporal_load(&xp[lane + 64]);
        const v4f a2 = __builtin_nontemporal_load(&xp[lane + 128]);
        const v4f a3 = __builtin_nontemporal_load(&xp[lane + 192]);
        float acc = a0.x*w0.x + a0.y*w0.y + a0.z*w0.z + a0.w*w0.w
                  + a1.x*w1.x + a1.y*w1.y + a1.z*w1.z + a1.w*w1.w
                  + a2.x*w2.x + a2.y*w2.y + a2.z*w2.z + a2.w*w2.w
                  + a3.x*w3.x + a3.y*w3.y + a3.z*w3.z + a3.w*w3.w;
#pragma unroll
        for (int off = 32; off > 0; off >>= 1)
            acc += __shfl_down(acc, off, 64);
        if (lane == 0)
            out[o] = acc + be;
    }
}

extern "C" void kernel_launch(void* const* d_in, const int* in_sizes, int n_in,
                              void* d_out, int out_size, void* d_ws, size_t ws_size,
                              hipStream_t stream) {
    const float* x    = (const float*)d_in[0];  // cell_states (B,S,E,H) fp32
    const float* W    = (const float*)d_in[1];  // (E,H) fp32
    const float* bias = (const float*)d_in[2];  // (E,) fp32
    float* out        = (float*)d_out;          // (B,S,E) fp32

    const int n_out = out_size;  // 131072
    // 2048 blocks x 256 threads = 8192 waves = 128 waves per e value.
    // 8 blocks/CU; each wave handles 16 rows.
    const int blocks = 2048;
    Cell_to_Entity_78735340470739_kernel<<<blocks, 256, 0, stream>>>(
        x, W, bias, out, n_out);
}